// Round 1
// baseline (704.106 us; speedup 1.0000x reference)
//
#include <hip/hip_runtime.h>
#include <hip/hip_bf16.h>

typedef unsigned short ushort_t;
typedef __bf16 bf16x8 __attribute__((ext_vector_type(8)));
typedef float f32x4 __attribute__((ext_vector_type(4)));

// ---------------- sizes ----------------
// x: (16,3,232,96,96) f32; W_in: (2048,2209); W_hid: (1024,2048); W_out: (4,39936)
// T=8, CHUNK=29, Dp=13, Hp=Wp=47, rows = T*B*39 = 4992, K=2209 padded to 2240
#define NROWS 4992
#define KPAD 2240
#define KREAL 2209
#define NH 2048

// ---------------- ws layout (bytes) ----------------
#define OFF_XS      ((size_t)0)                       // 4992*2240*2 = 22364160
#define OFF_WINB    ((size_t)22364160)                // 2048*2240*2 = 9175040
#define OFF_CURIN   ((size_t)31539200)                // 4992*2048*4 = 40894464
#define OFF_CNT1    ((size_t)72433664)                // 4992*4
#define OFF_BITS1   ((size_t)72453632)                // 4992*64*4
#define OFF_CNT2    ((size_t)73731584)                // 128*4
#define OFF_BITS2   ((size_t)73732096)                // 128*1248*4
#define ZERO_BYTES  ((size_t)(74371072 - 72433664))   // cnt1..bits2 contiguous
#define OFF_LIST1   ((size_t)74371072)                // 4992*64*4
#define OFF_LIST2   ((size_t)75649024)                // 128*256*4

// ---------------- W_in fp32 -> bf16 (K-padded) ----------------
__global__ __launch_bounds__(256) void convert_win(const float* __restrict__ W,
                                                   __hip_bfloat16* __restrict__ Wb) {
    int idx = blockIdx.x * 256 + threadIdx.x;      // < 2048*2240
    int n = idx / KPAD, k = idx - n * KPAD;
    float v = (k < KREAL) ? W[(size_t)n * KREAL + k] : 0.f;
    Wb[idx] = __float2bfloat16(v);
}

// ---------------- fused avgpool3d (4,4,4)/(2,2,2) -> xs bf16 [4992][2240] ----------------
__global__ __launch_bounds__(256) void pool_kernel(const float* __restrict__ x,
                                                   __hip_bfloat16* __restrict__ xs) {
    __shared__ float slice[9216];          // one 96x96 depth slice
    __shared__ float acc[2][2209];         // two in-flight d accumulators
    const int tid = threadIdx.x;
    const int blk = blockIdx.x;            // ((b*3)+c)*8 + t
    const int t = blk & 7;
    const int bc = blk >> 3;
    const int b = bc / 3, c = bc - b * 3;
    const float* xbase = x + ((size_t)bc * 232 + (size_t)t * 29) * 9216;

    for (int o = tid; o < 2209; o += 256) { acc[0][o] = 0.f; acc[1][o] = 0.f; }

    for (int z = 0; z < 28; ++z) {         // z=28 unused by VALID windows
        __syncthreads();                   // previous compute done with slice
        const float4* src = (const float4*)(xbase + (size_t)z * 9216);
        float4* dst = (float4*)slice;
#pragma unroll
        for (int kk = 0; kk < 9; ++kk) dst[tid + kk * 256] = src[tid + kk * 256];
        __syncthreads();

        const int dmin = (z >= 3) ? ((z - 2) >> 1) : 0;
        int dmax = z >> 1; if (dmax > 12) dmax = 12;
        const bool emit = (z >= 3) && (z & 1);
        const int dem = (z - 3) >> 1;      // d completed at this z (if emit)
        const int row = t * 624 + b * 39 + c * 13 + dem;

        for (int o = tid; o < 2209; o += 256) {
            int i = o / 47, j = o - i * 47;
            const float* p = slice + (2 * i) * 96 + 2 * j;
            float s = 0.f;
#pragma unroll
            for (int dy = 0; dy < 4; ++dy)
                s += p[dy * 96 + 0] + p[dy * 96 + 1] + p[dy * 96 + 2] + p[dy * 96 + 3];
            for (int d = dmin; d <= dmax; ++d) acc[d & 1][o] += s;
            if (emit) {
                int slot = dem & 1;
                xs[(size_t)row * KPAD + o] = __float2bfloat16(acc[slot][o] * 0.015625f);
                acc[slot][o] = 0.f;
            }
        }
        if (emit) {
            for (int o = KREAL + tid; o < KPAD; o += 256)
                xs[(size_t)row * KPAD + o] = __float2bfloat16(0.f);
        }
    }
}

// ---------------- bf16 MFMA GEMM: cur_in[4992][2048] = xs @ W_in^T ----------------
__global__ __launch_bounds__(256) void gemm_kernel(const ushort_t* __restrict__ A,
                                                   const ushort_t* __restrict__ B,
                                                   float* __restrict__ C) {
    __shared__ ushort_t As[64 * 40];   // 64 rows x 32 k, pad to 40 (2-way max)
    __shared__ ushort_t Bs[64 * 40];
    const int tid = threadIdx.x;
    const int m0 = blockIdx.y * 64, n0 = blockIdx.x * 64;
    const int lane = tid & 63, w = tid >> 6;
    const int wm = (w >> 1) * 32, wn = (w & 1) * 32;
    const int lr = lane & 15, quad = lane >> 4;

    f32x4 acc00 = {0.f,0.f,0.f,0.f}, acc01 = {0.f,0.f,0.f,0.f};
    f32x4 acc10 = {0.f,0.f,0.f,0.f}, acc11 = {0.f,0.f,0.f,0.f};

    const int r = tid >> 2, c8 = (tid & 3) * 8;
    const ushort_t* Ag = A + (size_t)(m0 + r) * KPAD + c8;
    const ushort_t* Bg = B + (size_t)(n0 + r) * KPAD + c8;
    ushort_t* Asw = &As[r * 40 + c8];
    ushort_t* Bsw = &Bs[r * 40 + c8];
    const ushort_t* Ar0 = &As[(wm + lr) * 40 + quad * 8];
    const ushort_t* Ar1 = &As[(wm + 16 + lr) * 40 + quad * 8];
    const ushort_t* Br0 = &Bs[(wn + lr) * 40 + quad * 8];
    const ushort_t* Br1 = &Bs[(wn + 16 + lr) * 40 + quad * 8];

    for (int k0 = 0; k0 < KPAD; k0 += 32) {
        __syncthreads();
        *(uint4*)Asw = *(const uint4*)(Ag + k0);
        *(uint4*)Bsw = *(const uint4*)(Bg + k0);
        __syncthreads();
        bf16x8 a0 = *(const bf16x8*)Ar0;
        bf16x8 a1 = *(const bf16x8*)Ar1;
        bf16x8 b0 = *(const bf16x8*)Br0;
        bf16x8 b1 = *(const bf16x8*)Br1;
        acc00 = __builtin_amdgcn_mfma_f32_16x16x32_bf16(a0, b0, acc00, 0, 0, 0);
        acc01 = __builtin_amdgcn_mfma_f32_16x16x32_bf16(a0, b1, acc01, 0, 0, 0);
        acc10 = __builtin_amdgcn_mfma_f32_16x16x32_bf16(a1, b0, acc10, 0, 0, 0);
        acc11 = __builtin_amdgcn_mfma_f32_16x16x32_bf16(a1, b1, acc11, 0, 0, 0);
    }
    const int colb = n0 + wn + lr;
    const int rowb = m0 + wm + quad * 4;
#pragma unroll
    for (int reg = 0; reg < 4; ++reg) {
        C[(size_t)(rowb + reg) * NH + colb]           = acc00[reg];
        C[(size_t)(rowb + reg) * NH + colb + 16]      = acc01[reg];
        C[(size_t)(rowb + 16 + reg) * NH + colb]      = acc10[reg];
        C[(size_t)(rowb + 16 + reg) * NH + colb + 16] = acc11[reg];
    }
}

// ---------------- layer-1 LIF scan -> sparse spike lists ----------------
__global__ __launch_bounds__(256) void lif1_kernel(const float* __restrict__ cur_in,
                                                   const float* __restrict__ b_in,
                                                   int* __restrict__ cnt1,
                                                   int* __restrict__ list1,
                                                   unsigned int* __restrict__ bits1) {
    const int h = blockIdx.x * 256 + threadIdx.x;   // [0,2048)
    const int row2 = blockIdx.y;                    // [0,624)  b*39+n
    const float bias = b_in[h];
    float m = 0.f;
#pragma unroll
    for (int t = 0; t < 8; ++t) {
        const int r = t * 624 + row2;
        float cur = cur_in[(size_t)r * NH + h] + bias;
        float reset = (m > 1.f) ? 1.f : 0.f;
        m = 0.9f * m + cur - reset;
        if (m > 1.f) {
            int idx = atomicAdd(&cnt1[r], 1);
            if (idx < 64) list1[r * 64 + idx] = h;
            atomicOr(&bits1[r * 64 + (h >> 5)], 1u << (h & 31));
        }
    }
}

// ---------------- layer-2 LIF (event-driven) ----------------
__global__ __launch_bounds__(256) void lif2_kernel(const float* __restrict__ W_hid,
                                                   const float* __restrict__ b_hid,
                                                   const int* __restrict__ cnt1,
                                                   const int* __restrict__ list1,
                                                   const unsigned int* __restrict__ bits1,
                                                   int* __restrict__ cnt2,
                                                   int* __restrict__ list2,
                                                   unsigned int* __restrict__ bits2) {
    const int g = blockIdx.x * 256 + threadIdx.x;   // [0,1024)
    const int row2 = blockIdx.y;                    // [0,624)
    const int b = row2 / 39, n = row2 - b * 39;
    const float* Wg = W_hid + (size_t)g * NH;
    const float bias = b_hid[g];
    float m = 0.f;
    for (int t = 0; t < 8; ++t) {
        const int r = t * 624 + row2;
        float cur = bias;
        int c = cnt1[r];
        if (c > 0) {
            if (c <= 64) {
                for (int i2 = 0; i2 < c; ++i2) cur += Wg[list1[r * 64 + i2]];
            } else {
                for (int w2 = 0; w2 < 64; ++w2) {
                    unsigned int v = bits1[r * 64 + w2];
                    while (v) { int h = w2 * 32 + __ffs(v) - 1; v &= v - 1; cur += Wg[h]; }
                }
            }
        }
        float reset = (m > 1.f) ? 1.f : 0.f;
        m = 0.9f * m + cur - reset;
        if (m > 1.f) {
            int rb = t * 16 + b;
            int fidx = n * 1024 + g;
            int idx = atomicAdd(&cnt2[rb], 1);
            if (idx < 256) list2[rb * 256 + idx] = fidx;
            atomicOr(&bits2[rb * 1248 + (fidx >> 5)], 1u << (fidx & 31));
        }
    }
}

// ---------------- layer-3 LIF -> output spikes ----------------
__global__ void lif3_kernel(const float* __restrict__ W_out,
                            const float* __restrict__ b_out,
                            const int* __restrict__ cnt2,
                            const int* __restrict__ list2,
                            const unsigned int* __restrict__ bits2,
                            float* __restrict__ out) {
    const int tid = threadIdx.x;        // 64 = 16 b x 4 o
    const int b = tid >> 2, o = tid & 3;
    const float* Wo = W_out + (size_t)o * 39936;
    const float bias = b_out[o];
    float m = 0.f;
    for (int t = 0; t < 8; ++t) {
        const int rb = t * 16 + b;
        float cur = bias;
        int c = cnt2[rb];
        if (c > 0) {
            if (c <= 256) {
                for (int i2 = 0; i2 < c; ++i2) cur += Wo[list2[rb * 256 + i2]];
            } else {
                for (int w2 = 0; w2 < 1248; ++w2) {
                    unsigned int v = bits2[rb * 1248 + w2];
                    while (v) { int f = w2 * 32 + __ffs(v) - 1; v &= v - 1; cur += Wo[f]; }
                }
            }
        }
        float reset = (m > 1.f) ? 1.f : 0.f;
        m = 0.9f * m + cur - reset;
        out[t * 64 + b * 4 + o] = (m > 1.f) ? 1.f : 0.f;
    }
}

extern "C" void kernel_launch(void* const* d_in, const int* in_sizes, int n_in,
                              void* d_out, int out_size, void* d_ws, size_t ws_size,
                              hipStream_t stream) {
    const float* x     = (const float*)d_in[0];
    const float* W_in  = (const float*)d_in[1];
    const float* b_in  = (const float*)d_in[2];
    const float* W_hid = (const float*)d_in[3];
    const float* b_hid = (const float*)d_in[4];
    const float* W_out = (const float*)d_in[5];
    const float* b_out = (const float*)d_in[6];
    float* out = (float*)d_out;
    char* ws = (char*)d_ws;

    __hip_bfloat16* xs_bf  = (__hip_bfloat16*)(ws + OFF_XS);
    __hip_bfloat16* winb   = (__hip_bfloat16*)(ws + OFF_WINB);
    float*          cur_in = (float*)(ws + OFF_CURIN);
    int*            cnt1   = (int*)(ws + OFF_CNT1);
    unsigned int*   bits1  = (unsigned int*)(ws + OFF_BITS1);
    int*            cnt2   = (int*)(ws + OFF_CNT2);
    unsigned int*   bits2  = (unsigned int*)(ws + OFF_BITS2);
    int*            list1  = (int*)(ws + OFF_LIST1);
    int*            list2  = (int*)(ws + OFF_LIST2);

    // zero the counters/bitmasks region (ws is poisoned before every call)
    hipMemsetAsync(ws + OFF_CNT1, 0, ZERO_BYTES, stream);

    convert_win<<<(2048 * KPAD) / 256, 256, 0, stream>>>(W_in, winb);
    pool_kernel<<<384, 256, 0, stream>>>(x, xs_bf);
    gemm_kernel<<<dim3(2048 / 64, NROWS / 64), 256, 0, stream>>>(
        (const ushort_t*)xs_bf, (const ushort_t*)winb, cur_in);
    lif1_kernel<<<dim3(8, 624), 256, 0, stream>>>(cur_in, b_in, cnt1, list1, bits1);
    lif2_kernel<<<dim3(4, 624), 256, 0, stream>>>(W_hid, b_hid, cnt1, list1, bits1,
                                                  cnt2, list2, bits2);
    lif3_kernel<<<1, 64, 0, stream>>>(W_out, b_out, cnt2, list2, bits2, out);
}

// Round 2
// 700.942 us; speedup vs baseline: 1.0045x; 1.0045x over previous
//
#include <hip/hip_runtime.h>
#include <hip/hip_bf16.h>

typedef unsigned short ushort_t;
typedef __bf16 bf16x8 __attribute__((ext_vector_type(8)));
typedef float f32x4 __attribute__((ext_vector_type(4)));

// ---------------- sizes ----------------
#define NROWS 4992
#define KPAD 2240
#define KREAL 2209
#define NH 2048

// ---------------- ws layout (bytes) ----------------
#define OFF_XS      ((size_t)0)                       // 4992*2240*2 = 22364160
#define OFF_WINB    ((size_t)22364160)                // 2048*2240*2 = 9175040
#define OFF_CURIN   ((size_t)31539200)                // 4992*2048*4 = 40894464
#define OFF_CNT1    ((size_t)72433664)                // 4992*4
#define OFF_BITS1   ((size_t)72453632)                // 4992*64*4
#define OFF_CNT2    ((size_t)73731584)                // 128*4
#define OFF_BITS2   ((size_t)73732096)                // 128*1248*4
#define ZERO_BYTES  ((size_t)(74371072 - 72433664))
#define OFF_LIST1   ((size_t)74371072)                // 4992*64*4
#define OFF_LIST2   ((size_t)75649024)                // 128*256*4

#define GLOAD16(g, l) __builtin_amdgcn_global_load_lds( \
    (const __attribute__((address_space(1))) void*)(g), \
    (__attribute__((address_space(3))) void*)(l), 16, 0, 0)

// ---------------- W_in fp32 -> bf16 (K-padded) ----------------
__global__ __launch_bounds__(256) void convert_win(const float* __restrict__ W,
                                                   __hip_bfloat16* __restrict__ Wb) {
    int idx = blockIdx.x * 256 + threadIdx.x;      // < 2048*2240
    int n = idx / KPAD, k = idx - n * KPAD;
    float v = (k < KREAL) ? W[(size_t)n * KREAL + k] : 0.f;
    Wb[idx] = __float2bfloat16(v);
}

// ---------------- fused avgpool3d, 4-band split: grid (384, 4) ----------------
__global__ __launch_bounds__(256) void pool_kernel(const float* __restrict__ x,
                                                   __hip_bfloat16* __restrict__ xs) {
    __shared__ float slice[26 * 96];       // band of one 96x96 depth slice
    __shared__ float acc[2][12 * 47];      // two in-flight d accumulators
    const int tid = threadIdx.x;
    const int band = blockIdx.y;           // 0..3
    const int blk = blockIdx.x;            // ((b*3)+c)*8 + t
    const int t = blk & 7;
    const int bc = blk >> 3;
    const int b = bc / 3, c = bc - b * 3;
    const int i0 = band * 12;
    const int ni = (band == 3) ? 11 : 12;
    const int nyf4 = (2 * ni + 2) * 24;    // float4 per band-slice
    const int nout = ni * 47;
    const float* xbase = x + ((size_t)bc * 232 + (size_t)t * 29) * 9216 + i0 * 192;

    for (int o = tid; o < nout; o += 256) { acc[0][o] = 0.f; acc[1][o] = 0.f; }

    for (int z = 0; z < 28; ++z) {
        __syncthreads();
        const float4* src = (const float4*)(xbase + (size_t)z * 9216);
        float4* dst = (float4*)slice;
        for (int idx = tid; idx < nyf4; idx += 256) dst[idx] = src[idx];
        __syncthreads();

        const int dmin = (z >= 3) ? ((z - 2) >> 1) : 0;
        int dmax = z >> 1; if (dmax > 12) dmax = 12;
        const bool emit = (z >= 3) && (z & 1);
        const int dem = (z - 3) >> 1;      // d completed at this z (if emit)
        const int row = t * 624 + b * 39 + c * 13 + dem;

        for (int o = tid; o < nout; o += 256) {
            int il = o / 47, j = o - il * 47;
            const float* p = slice + (2 * il) * 96 + 2 * j;
            float s = 0.f;
#pragma unroll
            for (int dy = 0; dy < 4; ++dy)
                s += p[dy * 96 + 0] + p[dy * 96 + 1] + p[dy * 96 + 2] + p[dy * 96 + 3];
            for (int d = dmin; d <= dmax; ++d) acc[d & 1][o] += s;
            if (emit) {
                int slot = dem & 1;
                xs[(size_t)row * KPAD + i0 * 47 + o] = __float2bfloat16(acc[slot][o] * 0.015625f);
                acc[slot][o] = 0.f;
            }
        }
        if (emit && band == 0 && tid < KPAD - KREAL) {
            xs[(size_t)row * KPAD + KREAL + tid] = __float2bfloat16(0.f);
        }
    }
}

// ---------------- bf16 MFMA GEMM 128x128 tile + global_load_lds ----------------
#define BM 128
#define BN 128
#define BK 32
__global__ __launch_bounds__(256) void gemm_kernel(const ushort_t* __restrict__ A,
                                                   const ushort_t* __restrict__ B,
                                                   float* __restrict__ C) {
    __shared__ ushort_t As[BM * BK];   // 8 KB, row-major [row][32], NO pad (lds-dma)
    __shared__ ushort_t Bs[BN * BK];   // 8 KB
    const int tid = threadIdx.x;
    const int m0 = blockIdx.y * BM, n0 = blockIdx.x * BN;
    const int lane = tid & 63, w = tid >> 6;
    const int wm = (w >> 1) * 64, wn = (w & 1) * 64;
    const int lr = lane & 15, quad = lane >> 4;

    f32x4 acc[4][4] = {};

    const int srow = tid >> 2;           // 0..63
    const int sk = (tid & 3) * 8;        // 0,8,16,24
    const ushort_t* Ag0 = A + (size_t)(m0 + srow) * KPAD + sk;
    const ushort_t* Ag1 = A + (size_t)(m0 + 64 + srow) * KPAD + sk;
    const ushort_t* Bg0 = B + (size_t)(n0 + srow) * KPAD + sk;
    const ushort_t* Bg1 = B + (size_t)(n0 + 64 + srow) * KPAD + sk;
    ushort_t* Asl0 = &As[srow * BK + sk];          // byte off = tid*16
    ushort_t* Asl1 = &As[(64 + srow) * BK + sk];
    ushort_t* Bsl0 = &Bs[srow * BK + sk];
    ushort_t* Bsl1 = &Bs[(64 + srow) * BK + sk];

    for (int k0 = 0; k0 < KPAD; k0 += BK) {
        __syncthreads();
        GLOAD16(Ag0 + k0, Asl0);
        GLOAD16(Ag1 + k0, Asl1);
        GLOAD16(Bg0 + k0, Bsl0);
        GLOAD16(Bg1 + k0, Bsl1);
        __syncthreads();
        bf16x8 af[4], bfr[4];
#pragma unroll
        for (int i = 0; i < 4; ++i)
            af[i] = *(const bf16x8*)&As[(wm + i * 16 + lr) * BK + quad * 8];
#pragma unroll
        for (int j = 0; j < 4; ++j)
            bfr[j] = *(const bf16x8*)&Bs[(wn + j * 16 + lr) * BK + quad * 8];
#pragma unroll
        for (int i = 0; i < 4; ++i)
#pragma unroll
            for (int j = 0; j < 4; ++j)
                acc[i][j] = __builtin_amdgcn_mfma_f32_16x16x32_bf16(af[i], bfr[j], acc[i][j], 0, 0, 0);
    }
#pragma unroll
    for (int i = 0; i < 4; ++i) {
        const int row = m0 + wm + i * 16 + quad * 4;
#pragma unroll
        for (int j = 0; j < 4; ++j) {
            const int col = n0 + wn + j * 16 + lr;
#pragma unroll
            for (int reg = 0; reg < 4; ++reg)
                C[(size_t)(row + reg) * NH + col] = acc[i][j][reg];
        }
    }
}

// ---------------- layer-1 LIF scan -> sparse spike lists ----------------
__global__ __launch_bounds__(256) void lif1_kernel(const float* __restrict__ cur_in,
                                                   const float* __restrict__ b_in,
                                                   int* __restrict__ cnt1,
                                                   int* __restrict__ list1,
                                                   unsigned int* __restrict__ bits1) {
    const int h = blockIdx.x * 256 + threadIdx.x;   // [0,2048)
    const int row2 = blockIdx.y;                    // [0,624)
    const float bias = b_in[h];
    float m = 0.f;
#pragma unroll
    for (int t = 0; t < 8; ++t) {
        const int r = t * 624 + row2;
        float cur = cur_in[(size_t)r * NH + h] + bias;
        float reset = (m > 1.f) ? 1.f : 0.f;
        m = 0.9f * m + cur - reset;
        if (m > 1.f) {
            int idx = atomicAdd(&cnt1[r], 1);
            if (idx < 64) list1[r * 64 + idx] = h;
            atomicOr(&bits1[r * 64 + (h >> 5)], 1u << (h & 31));
        }
    }
}

// ---------------- layer-2 LIF (event-driven) ----------------
__global__ __launch_bounds__(256) void lif2_kernel(const float* __restrict__ W_hid,
                                                   const float* __restrict__ b_hid,
                                                   const int* __restrict__ cnt1,
                                                   const int* __restrict__ list1,
                                                   const unsigned int* __restrict__ bits1,
                                                   int* __restrict__ cnt2,
                                                   int* __restrict__ list2,
                                                   unsigned int* __restrict__ bits2) {
    const int g = blockIdx.x * 256 + threadIdx.x;   // [0,1024)
    const int row2 = blockIdx.y;                    // [0,624)
    const int b = row2 / 39, n = row2 - b * 39;
    const float* Wg = W_hid + (size_t)g * NH;
    const float bias = b_hid[g];
    float m = 0.f;
    for (int t = 0; t < 8; ++t) {
        const int r = t * 624 + row2;
        float cur = bias;
        int c = cnt1[r];
        if (c > 0) {
            if (c <= 64) {
                for (int i2 = 0; i2 < c; ++i2) cur += Wg[list1[r * 64 + i2]];
            } else {
                for (int w2 = 0; w2 < 64; ++w2) {
                    unsigned int v = bits1[r * 64 + w2];
                    while (v) { int h = w2 * 32 + __ffs(v) - 1; v &= v - 1; cur += Wg[h]; }
                }
            }
        }
        float reset = (m > 1.f) ? 1.f : 0.f;
        m = 0.9f * m + cur - reset;
        if (m > 1.f) {
            int rb = t * 16 + b;
            int fidx = n * 1024 + g;
            int idx = atomicAdd(&cnt2[rb], 1);
            if (idx < 256) list2[rb * 256 + idx] = fidx;
            atomicOr(&bits2[rb * 1248 + (fidx >> 5)], 1u << (fidx & 31));
        }
    }
}

// ---------------- layer-3 LIF -> output spikes ----------------
__global__ void lif3_kernel(const float* __restrict__ W_out,
                            const float* __restrict__ b_out,
                            const int* __restrict__ cnt2,
                            const int* __restrict__ list2,
                            const unsigned int* __restrict__ bits2,
                            float* __restrict__ out) {
    const int tid = threadIdx.x;        // 64 = 16 b x 4 o
    const int b = tid >> 2, o = tid & 3;
    const float* Wo = W_out + (size_t)o * 39936;
    const float bias = b_out[o];
    float m = 0.f;
    for (int t = 0; t < 8; ++t) {
        const int rb = t * 16 + b;
        float cur = bias;
        int c = cnt2[rb];
        if (c > 0) {
            if (c <= 256) {
                for (int i2 = 0; i2 < c; ++i2) cur += Wo[list2[rb * 256 + i2]];
            } else {
                for (int w2 = 0; w2 < 1248; ++w2) {
                    unsigned int v = bits2[rb * 1248 + w2];
                    while (v) { int f = w2 * 32 + __ffs(v) - 1; v &= v - 1; cur += Wo[f]; }
                }
            }
        }
        float reset = (m > 1.f) ? 1.f : 0.f;
        m = 0.9f * m + cur - reset;
        out[t * 64 + b * 4 + o] = (m > 1.f) ? 1.f : 0.f;
    }
}

extern "C" void kernel_launch(void* const* d_in, const int* in_sizes, int n_in,
                              void* d_out, int out_size, void* d_ws, size_t ws_size,
                              hipStream_t stream) {
    const float* x     = (const float*)d_in[0];
    const float* W_in  = (const float*)d_in[1];
    const float* b_in  = (const float*)d_in[2];
    const float* W_hid = (const float*)d_in[3];
    const float* b_hid = (const float*)d_in[4];
    const float* W_out = (const float*)d_in[5];
    const float* b_out = (const float*)d_in[6];
    float* out = (float*)d_out;
    char* ws = (char*)d_ws;

    __hip_bfloat16* xs_bf  = (__hip_bfloat16*)(ws + OFF_XS);
    __hip_bfloat16* winb   = (__hip_bfloat16*)(ws + OFF_WINB);
    float*          cur_in = (float*)(ws + OFF_CURIN);
    int*            cnt1   = (int*)(ws + OFF_CNT1);
    unsigned int*   bits1  = (unsigned int*)(ws + OFF_BITS1);
    int*            cnt2   = (int*)(ws + OFF_CNT2);
    unsigned int*   bits2  = (unsigned int*)(ws + OFF_BITS2);
    int*            list1  = (int*)(ws + OFF_LIST1);
    int*            list2  = (int*)(ws + OFF_LIST2);

    hipMemsetAsync(ws + OFF_CNT1, 0, ZERO_BYTES, stream);

    convert_win<<<(2048 * KPAD) / 256, 256, 0, stream>>>(W_in, winb);
    pool_kernel<<<dim3(384, 4), 256, 0, stream>>>(x, xs_bf);
    gemm_kernel<<<dim3(NH / BN, NROWS / BM), 256, 0, stream>>>(
        (const ushort_t*)xs_bf, (const ushort_t*)winb, cur_in);
    lif1_kernel<<<dim3(8, 624), 256, 0, stream>>>(cur_in, b_in, cnt1, list1, bits1);
    lif2_kernel<<<dim3(4, 624), 256, 0, stream>>>(W_hid, b_hid, cnt1, list1, bits1,
                                                  cnt2, list2, bits2);
    lif3_kernel<<<1, 64, 0, stream>>>(W_out, b_out, cnt2, list2, bits2, out);
}

// Round 3
// 651.451 us; speedup vs baseline: 1.0808x; 1.0760x over previous
//
#include <hip/hip_runtime.h>
#include <hip/hip_bf16.h>

typedef unsigned short ushort_t;
typedef __bf16 bf16x8 __attribute__((ext_vector_type(8)));
typedef float f32x4 __attribute__((ext_vector_type(4)));

// ---------------- sizes ----------------
#define NROWS 4992
#define KPAD 2240
#define KREAL 2209
#define NH 2048

// ---------------- ws layout (bytes) ----------------
#define OFF_XS      ((size_t)0)                       // 4992*2240*2 = 22364160
#define OFF_WINB    ((size_t)22364160)                // 2048*2240*2 = 9175040
#define OFF_CNT1    ((size_t)72433664)                // 4992*4
#define OFF_BITS1   ((size_t)72453632)                // 4992*64*4
#define OFF_CNT2    ((size_t)73731584)                // 128*4
#define OFF_BITS2   ((size_t)73732096)                // 128*1248*4
#define ZERO_BYTES  ((size_t)(74371072 - 72433664))
#define OFF_LIST1   ((size_t)74371072)                // 4992*64*4
#define OFF_LIST2   ((size_t)75649024)                // 128*256*4

#define GLOAD16(g, l) __builtin_amdgcn_global_load_lds( \
    (const __attribute__((address_space(1))) void*)(g), \
    (__attribute__((address_space(3))) void*)(l), 16, 0, 0)

// Row permutation: xs row m encodes (row2, t) such that in the 128-row GEMM
// tile the 8 timesteps of one row2 all live in ONE thread's acc registers:
//   m = (row2>>4)*128 + ((row2>>3)&1)*64 + i*16 + q*4 + reg
//   with q = (row2&7)>>1, i = (row2&1... ) see below
__device__ __forceinline__ int perm_row(int row2, int t) {
    const int blkr = row2 >> 4, half = (row2 >> 3) & 1, r8 = row2 & 7;
    const int q = r8 >> 1, il2 = r8 & 1;
    const int i_ = il2 | ((t >> 2) << 1), reg = t & 3;
    return blkr * 128 + half * 64 + i_ * 16 + q * 4 + reg;
}

// ---------------- W_in fp32 -> bf16 (K-padded) ----------------
__global__ __launch_bounds__(256) void convert_win(const float* __restrict__ W,
                                                   __hip_bfloat16* __restrict__ Wb) {
    int idx = blockIdx.x * 256 + threadIdx.x;      // < 2048*2240
    int n = idx / KPAD, k = idx - n * KPAD;
    float v = (k < KREAL) ? W[(size_t)n * KREAL + k] : 0.f;
    Wb[idx] = __float2bfloat16(v);
}

// ---------------- fused avgpool3d, 4-band split: grid (384, 4) ----------------
__global__ __launch_bounds__(256) void pool_kernel(const float* __restrict__ x,
                                                   __hip_bfloat16* __restrict__ xs) {
    __shared__ float slice[26 * 96];       // band of one 96x96 depth slice
    __shared__ float acc[2][12 * 47];      // two in-flight d accumulators
    const int tid = threadIdx.x;
    const int band = blockIdx.y;           // 0..3
    const int blk = blockIdx.x;            // ((b*3)+c)*8 + t
    const int t = blk & 7;
    const int bc = blk >> 3;
    const int b = bc / 3, c = bc - b * 3;
    const int i0 = band * 12;
    const int ni = (band == 3) ? 11 : 12;
    const int nyf4 = (2 * ni + 2) * 24;    // float4 per band-slice
    const int nout = ni * 47;
    const float* xbase = x + ((size_t)bc * 232 + (size_t)t * 29) * 9216 + i0 * 192;

    // hoist per-thread output decomposition (<=3 outputs/thread)
    int myo[3], mypo[3];
    int nmy = 0;
    for (int o = tid; o < nout; o += 256) {
        int il = o / 47, j = o - il * 47;
        myo[nmy] = o;
        mypo[nmy] = (2 * il) * 96 + 2 * j;
        ++nmy;
    }

    for (int o = tid; o < nout; o += 256) { acc[0][o] = 0.f; acc[1][o] = 0.f; }

    for (int z = 0; z < 28; ++z) {
        __syncthreads();
        const float4* src = (const float4*)(xbase + (size_t)z * 9216);
        float4* dst = (float4*)slice;
        for (int idx = tid; idx < nyf4; idx += 256) dst[idx] = src[idx];
        __syncthreads();

        const int dmin = (z >= 3) ? ((z - 2) >> 1) : 0;
        int dmax = z >> 1; if (dmax > 12) dmax = 12;
        const bool emit = (z >= 3) && (z & 1);
        const int dem = (z - 3) >> 1;      // d completed at this z (if emit)
        int row = 0;
        if (emit) row = perm_row(b * 39 + c * 13 + dem, t);

        for (int s = 0; s < nmy; ++s) {
            const int o = myo[s];
            const float* p = slice + mypo[s];
            float sum = 0.f;
#pragma unroll
            for (int dy = 0; dy < 4; ++dy)
                sum += p[dy * 96 + 0] + p[dy * 96 + 1] + p[dy * 96 + 2] + p[dy * 96 + 3];
            for (int d = dmin; d <= dmax; ++d) acc[d & 1][o] += sum;
            if (emit) {
                int slot = dem & 1;
                xs[(size_t)row * KPAD + i0 * 47 + o] = __float2bfloat16(acc[slot][o] * 0.015625f);
                acc[slot][o] = 0.f;
            }
        }
        if (emit && band == 0 && tid < KPAD - KREAL) {
            xs[(size_t)row * KPAD + KREAL + tid] = __float2bfloat16(0.f);
        }
    }
}

// ------- bf16 MFMA GEMM 128x128 + fused bias + layer-1 LIF scan epilogue -------
#define BM 128
#define BN 128
#define BK 32
__global__ __launch_bounds__(256) void gemm_lif1_kernel(const ushort_t* __restrict__ A,
                                                        const ushort_t* __restrict__ B,
                                                        const float* __restrict__ b_in,
                                                        int* __restrict__ cnt1,
                                                        int* __restrict__ list1,
                                                        unsigned int* __restrict__ bits1) {
    __shared__ ushort_t As[BM * BK];   // 8 KB row-major [row][32], NO pad (lds-dma)
    __shared__ ushort_t Bs[BN * BK];   // 8 KB
    const int tid = threadIdx.x;
    const int m0 = blockIdx.y * BM, n0 = blockIdx.x * BN;
    const int lane = tid & 63, w = tid >> 6;
    const int wm = (w >> 1) * 64, wn = (w & 1) * 64;
    const int lr = lane & 15, quad = lane >> 4;

    f32x4 acc[4][4] = {};

    const int srow = tid >> 2;           // 0..63
    const int sk = (tid & 3) * 8;        // 0,8,16,24
    const ushort_t* Ag0 = A + (size_t)(m0 + srow) * KPAD + sk;
    const ushort_t* Ag1 = A + (size_t)(m0 + 64 + srow) * KPAD + sk;
    const ushort_t* Bg0 = B + (size_t)(n0 + srow) * KPAD + sk;
    const ushort_t* Bg1 = B + (size_t)(n0 + 64 + srow) * KPAD + sk;
    ushort_t* Asl0 = &As[srow * BK + sk];          // byte off = tid*16
    ushort_t* Asl1 = &As[(64 + srow) * BK + sk];
    ushort_t* Bsl0 = &Bs[srow * BK + sk];
    ushort_t* Bsl1 = &Bs[(64 + srow) * BK + sk];

    for (int k0 = 0; k0 < KPAD; k0 += BK) {
        __syncthreads();
        GLOAD16(Ag0 + k0, Asl0);
        GLOAD16(Ag1 + k0, Asl1);
        GLOAD16(Bg0 + k0, Bsl0);
        GLOAD16(Bg1 + k0, Bsl1);
        __syncthreads();
        bf16x8 af[4], bfr[4];
#pragma unroll
        for (int i = 0; i < 4; ++i)
            af[i] = *(const bf16x8*)&As[(wm + i * 16 + lr) * BK + quad * 8];
#pragma unroll
        for (int j = 0; j < 4; ++j)
            bfr[j] = *(const bf16x8*)&Bs[(wn + j * 16 + lr) * BK + quad * 8];
#pragma unroll
        for (int i = 0; i < 4; ++i)
#pragma unroll
            for (int j = 0; j < 4; ++j)
                acc[i][j] = __builtin_amdgcn_mfma_f32_16x16x32_bf16(af[i], bfr[j], acc[i][j], 0, 0, 0);
    }

    // Epilogue: rows of this tile are permuted so thread (quad,lr) of wave w
    // holds, for row2_local = quad*2+rr (rr=0,1), all 8 timesteps:
    //   t = (i>>1)*4 + reg  ->  acc[rr + 2*(t>>2)][j][t&3]
    const int row2_base = blockIdx.y * 16 + (w >> 1) * 8 + quad * 2;
#pragma unroll
    for (int j = 0; j < 4; ++j) {
        const int h = n0 + wn + j * 16 + lr;
        const float bias = b_in[h];
#pragma unroll
        for (int rr = 0; rr < 2; ++rr) {
            const int r2 = row2_base + rr;
            float m = 0.f;
#pragma unroll
            for (int t = 0; t < 8; ++t) {
                float cur = acc[rr + 2 * (t >> 2)][j][t & 3] + bias;
                float reset = (m > 1.f) ? 1.f : 0.f;
                m = 0.9f * m + cur - reset;
                if (m > 1.f) {
                    const int r = t * 624 + r2;
                    int idx = atomicAdd(&cnt1[r], 1);
                    if (idx < 64) list1[r * 64 + idx] = h;
                    atomicOr(&bits1[r * 64 + (h >> 5)], 1u << (h & 31));
                }
            }
        }
    }
}

// ---------------- layer-2 LIF (event-driven) ----------------
__global__ __launch_bounds__(256) void lif2_kernel(const float* __restrict__ W_hid,
                                                   const float* __restrict__ b_hid,
                                                   const int* __restrict__ cnt1,
                                                   const int* __restrict__ list1,
                                                   const unsigned int* __restrict__ bits1,
                                                   int* __restrict__ cnt2,
                                                   int* __restrict__ list2,
                                                   unsigned int* __restrict__ bits2) {
    const int g = blockIdx.x * 256 + threadIdx.x;   // [0,1024)
    const int row2 = blockIdx.y;                    // [0,624)
    const int b = row2 / 39, n = row2 - b * 39;
    const float* Wg = W_hid + (size_t)g * NH;
    const float bias = b_hid[g];
    float m = 0.f;
    for (int t = 0; t < 8; ++t) {
        const int r = t * 624 + row2;
        float cur = bias;
        int c = cnt1[r];
        if (c > 0) {
            if (c <= 64) {
                for (int i2 = 0; i2 < c; ++i2) cur += Wg[list1[r * 64 + i2]];
            } else {
                for (int w2 = 0; w2 < 64; ++w2) {
                    unsigned int v = bits1[r * 64 + w2];
                    while (v) { int h = w2 * 32 + __ffs(v) - 1; v &= v - 1; cur += Wg[h]; }
                }
            }
        }
        float reset = (m > 1.f) ? 1.f : 0.f;
        m = 0.9f * m + cur - reset;
        if (m > 1.f) {
            int rb = t * 16 + b;
            int fidx = n * 1024 + g;
            int idx = atomicAdd(&cnt2[rb], 1);
            if (idx < 256) list2[rb * 256 + idx] = fidx;
            atomicOr(&bits2[rb * 1248 + (fidx >> 5)], 1u << (fidx & 31));
        }
    }
}

// ---------------- layer-3 LIF -> output spikes ----------------
__global__ void lif3_kernel(const float* __restrict__ W_out,
                            const float* __restrict__ b_out,
                            const int* __restrict__ cnt2,
                            const int* __restrict__ list2,
                            const unsigned int* __restrict__ bits2,
                            float* __restrict__ out) {
    const int tid = threadIdx.x;        // 64 = 16 b x 4 o
    const int b = tid >> 2, o = tid & 3;
    const float* Wo = W_out + (size_t)o * 39936;
    const float bias = b_out[o];
    float m = 0.f;
    for (int t = 0; t < 8; ++t) {
        const int rb = t * 16 + b;
        float cur = bias;
        int c = cnt2[rb];
        if (c > 0) {
            if (c <= 256) {
                for (int i2 = 0; i2 < c; ++i2) cur += Wo[list2[rb * 256 + i2]];
            } else {
                for (int w2 = 0; w2 < 1248; ++w2) {
                    unsigned int v = bits2[rb * 1248 + w2];
                    while (v) { int f = w2 * 32 + __ffs(v) - 1; v &= v - 1; cur += Wo[f]; }
                }
            }
        }
        float reset = (m > 1.f) ? 1.f : 0.f;
        m = 0.9f * m + cur - reset;
        out[t * 64 + b * 4 + o] = (m > 1.f) ? 1.f : 0.f;
    }
}

extern "C" void kernel_launch(void* const* d_in, const int* in_sizes, int n_in,
                              void* d_out, int out_size, void* d_ws, size_t ws_size,
                              hipStream_t stream) {
    const float* x     = (const float*)d_in[0];
    const float* W_in  = (const float*)d_in[1];
    const float* b_in  = (const float*)d_in[2];
    const float* W_hid = (const float*)d_in[3];
    const float* b_hid = (const float*)d_in[4];
    const float* W_out = (const float*)d_in[5];
    const float* b_out = (const float*)d_in[6];
    float* out = (float*)d_out;
    char* ws = (char*)d_ws;

    __hip_bfloat16* xs_bf  = (__hip_bfloat16*)(ws + OFF_XS);
    __hip_bfloat16* winb   = (__hip_bfloat16*)(ws + OFF_WINB);
    int*            cnt1   = (int*)(ws + OFF_CNT1);
    unsigned int*   bits1  = (unsigned int*)(ws + OFF_BITS1);
    int*            cnt2   = (int*)(ws + OFF_CNT2);
    unsigned int*   bits2  = (unsigned int*)(ws + OFF_BITS2);
    int*            list1  = (int*)(ws + OFF_LIST1);
    int*            list2  = (int*)(ws + OFF_LIST2);

    hipMemsetAsync(ws + OFF_CNT1, 0, ZERO_BYTES, stream);

    convert_win<<<(2048 * KPAD) / 256, 256, 0, stream>>>(W_in, winb);
    pool_kernel<<<dim3(384, 4), 256, 0, stream>>>(x, xs_bf);
    gemm_lif1_kernel<<<dim3(NH / BN, NROWS / BM), 256, 0, stream>>>(
        (const ushort_t*)xs_bf, (const ushort_t*)winb, b_in, cnt1, list1, bits1);
    lif2_kernel<<<dim3(4, 624), 256, 0, stream>>>(W_hid, b_hid, cnt1, list1, bits1,
                                                  cnt2, list2, bits2);
    lif3_kernel<<<1, 64, 0, stream>>>(W_out, b_out, cnt2, list2, bits2, out);
}